// Round 1
// baseline (2068.395 us; speedup 1.0000x reference)
//
#include <hip/hip_runtime.h>

typedef unsigned short u16;
typedef unsigned int u32;

#define FIN 512
#define HID 16
#define NCLS 64

// flags: [0]=edge-int64 [1]=x-fp32 [2]=weights-fp32 [3]=x-zero [4]=w1-zero
//        [8]=anomaly    [9]=anomaly code
__device__ __forceinline__ float bf2f_raw(u16 u) {
    u32 x = ((u32)u) << 16;
    float f; __builtin_memcpy(&f, &x, 4); return f;
}
// adaptive float load: element i of a logical float array stored fp32 or bf16
__device__ __forceinline__ float ldf(const void* p, long long i, int f32) {
    return f32 ? ((const float*)p)[i] : bf2f_raw(((const u16*)p)[i]);
}

// ---- probe raw bits of x, w1, edges; set flags ----
__global__ void k_probe(const void* x, const void* w1, const int* eidx, int E,
                        int* flags) {
    __shared__ int nz_x, nz_w, weird_x, weird_w, odd_nz;
    if (threadIdx.x == 0) { nz_x = 0; nz_w = 0; weird_x = 0; weird_w = 0; odd_nz = 0; }
    __syncthreads();
    const u16* xu = (const u16*)x;
    const u16* wu = (const u16*)w1;
    // "weird as bf16" = denormal or |v|>=2^65 — impossible for N(0,~1) data
    for (int i = threadIdx.x; i < 8192; i += 256) {
        u16 u = xu[i];
        if (u) atomicOr(&nz_x, 1);
        int e = (u >> 7) & 0xff;
        if ((e == 0 && (u & 0x7f)) || e >= 0xC0) atomicAdd(&weird_x, 1);
        u16 w = wu[i];
        if (w) atomicOr(&nz_w, 1);
        int ew = (w >> 7) & 0xff;
        if ((ew == 0 && (w & 0x7f)) || ew >= 0xC0) atomicAdd(&weird_w, 1);
    }
    // int64 little-endian nonneg < 2^31 => odd 32-bit words all zero
    int lim = (2 * E < 4096) ? 2 * E : 4096;
    for (int i = 1 + 2 * (int)threadIdx.x; i < lim; i += 512) {
        if (eidx[i] != 0) atomicOr(&odd_nz, 1);
    }
    __syncthreads();
    if (threadIdx.x == 0) {
        flags[0] = (odd_nz == 0) ? 1 : 0;
        flags[1] = (weird_x > 64) ? 1 : 0;
        flags[2] = (weird_w > 64) ? 1 : 0;
        flags[3] = (nz_x == 0) ? 1 : 0;
        flags[4] = (nz_w == 0) ? 1 : 0;
    }
}

__device__ __forceinline__ int ld_src(const int* eidx, int E, int e, int f64) {
    return f64 ? eidx[2LL * e] : eidx[e];
}
__device__ __forceinline__ int ld_dst(const int* eidx, int E, int e, int f64) {
    return f64 ? eidx[2LL * E + 2LL * e] : eidx[(long long)E + e];
}

// zero degf[n], h1[n*16], h3p[n*16]
__global__ void k_zero(float* degf, float* h1, float* h3p, int n) {
    int i = blockIdx.x * 256 + threadIdx.x;
    if (i < n) degf[i] = 0.0f;
    if (i < n * HID) { h1[i] = 0.0f; h3p[i] = 0.0f; }
}

__global__ void k_deg(const int* eidx, const int* flags, float* degf, int E, int n) {
    int e = blockIdx.x * 256 + threadIdx.x;
    if (e >= E) return;
    int d = ld_dst(eidx, E, e, flags[0]);
    if ((unsigned)d < (unsigned)n) atomicAdd(&degf[d], 1.0f);
}

__global__ void k_dinv(const float* degf, float* dinv, int n) {
    int i = blockIdx.x * 256 + threadIdx.x;
    if (i < n) dinv[i] = rsqrtf(degf[i] + 1.0f);  // +1 self-loop
}

// h0[n,16] = x[n,512] @ W1[512,16]
__global__ void k_gemm1(const void* x, const void* w1, const int* flags,
                        float* h0, int n) {
    int t = blockIdx.x * 256 + threadIdx.x;
    if (t >= n * HID) return;
    int node = t >> 4;
    int f = t & 15;
    int fx = flags[1], fw = flags[2];
    long long xb = (long long)node * FIN;
    float acc = 0.0f;
    for (int k = 0; k < FIN; k++) {
        acc += ldf(x, xb + k, fx) * ldf(w1, (long long)k * HID + f, fw);
    }
    h0[t] = acc;
}

// unified 16-wide propagation: h_out[d,:] += dinv_s*dinv_d * h_in[s,:]
// one thread per (edge, float4-group): 4 lanes cover one 64B row — coalesced
__global__ void k_scatter16(const int* eidx, const int* flags, const float* dinv,
                            const float* h_in, float* h_out, int E, int n) {
    long long t = (long long)blockIdx.x * 256 + threadIdx.x;
    if (t >= (long long)E * 4) return;  // 12.8M threads, 51.2M atomics
    int e = (int)(t >> 2);
    int g = (int)(t & 3);
    int f64 = flags[0];
    int s = ld_src(eidx, E, e, f64);
    int d = ld_dst(eidx, E, e, f64);
    if ((unsigned)s >= (unsigned)n || (unsigned)d >= (unsigned)n) return;
    float w = dinv[s] * dinv[d];
    const float4 v = *(const float4*)(h_in + (long long)s * HID + g * 4);
    float* o = h_out + (long long)d * HID + g * 4;
    atomicAdd(o + 0, w * v.x);
    atomicAdd(o + 1, w * v.y);
    atomicAdd(o + 2, w * v.z);
    atomicAdd(o + 3, w * v.w);
}

// h2p[n,16] = relu(h1 + di^2*h0 + b1)   (self-loop added analytically)
__global__ void k_relu(const float* h0, const float* h1, const float* dinv,
                       const void* b1, const int* flags, float* h2p, int n) {
    int t = blockIdx.x * 256 + threadIdx.x;
    if (t >= n * HID) return;
    int node = t >> 4;
    int k = t & 15;
    float di = dinv[node];
    float v = h1[t] + di * di * h0[t] + ldf(b1, k, flags[2]);
    h2p[t] = fmaxf(v, 0.0f);
}

// ---- post-pipeline anomaly check; beacon only when something is wrong ----
__global__ void k_check(const int* eidx, const float* h0, const float* h3p,
                        int* flags, int E, int n) {
    __shared__ int h0nz, h3nz, dstz;
    if (threadIdx.x == 0) { h0nz = 0; h3nz = 0; dstz = 0; }
    __syncthreads();
    for (int i = threadIdx.x; i < 4096; i += 256) {
        if (h0[i] != 0.0f) atomicOr(&h0nz, 1);
        if (h3p[i] != 0.0f) atomicOr(&h3nz, 1);
    }
    int f64 = flags[0];
    for (int e = threadIdx.x; e < 2048; e += 256) {
        if (ld_dst(eidx, E, e, f64) == 0) atomicAdd(&dstz, 1);
    }
    __syncthreads();
    if (threadIdx.x == 0) {
        int b0 = flags[3];             // x sample all zero
        int b1 = flags[4];             // w1 sample all zero
        int b2 = (dstz > 102);         // >5% of dst sample == 0 (edge misread)
        int b3 = (h0nz == 0);          // gemm1 produced nothing
        int b4 = (h3nz == 0);          // propagation produced nothing
        int b5 = flags[1];             // info: x fp32
        int b6 = flags[2];             // info: weights fp32
        int b7 = flags[0];             // info: edges int64
        flags[9] = b0 | (b1 << 1) | (b2 << 2) | (b3 << 3) | (b4 << 4) |
                   (b5 << 5) | (b6 << 6) | (b7 << 7);
        flags[8] = (b0 | b1 | b2 | b3 | b4) ? 1 : 0;
    }
}

// out[n,64] = (h3p + di^2*h2p) @ W2 + b2   (propagate-then-multiply: A(HW)= (AH)W)
__global__ void SimplifiedGCN_5574867550498_kernel(
        const float* h2p, const float* h3p, const float* dinv,
        const void* w2, const void* b2, const int* flags, float* out, int n) {
    int t = blockIdx.x * 256 + threadIdx.x;
    if (t >= n * NCLS) return;
    int node = t >> 6;
    int c = t & 63;
    int fw = flags[2];
    float di = dinv[node];
    float di2 = di * di;
    float acc = ldf(b2, c, fw);
    for (int k = 0; k < HID; k++) {
        float g = h3p[node * HID + k] + di2 * h2p[node * HID + k];
        acc += g * ldf(w2, (long long)k * NCLS + c, fw);
    }
    if (t == 0 && flags[8]) acc = 4096.0f + 2.0f * (float)flags[9];  // beacon
    out[t] = acc;
}

extern "C" void kernel_launch(void* const* d_in, const int* in_sizes, int n_in,
                              void* d_out, int out_size, void* d_ws, size_t ws_size,
                              hipStream_t stream) {
    const void* x = d_in[0];
    const int* eidx = (const int*)d_in[1];
    const void* w1 = d_in[2];
    const void* b1 = d_in[3];
    const void* w2 = d_in[4];
    const void* b2 = d_in[5];
    float* out = (float*)d_out;

    int n = in_sizes[0] / FIN;
    int E = in_sizes[1] / 2;
    int total_out = n * NCLS;
    int nb_out = (total_out + 255) / 256;
    size_t out_bytes = (size_t)total_out * 4;

    // ~48.5 everywhere if later kernels never write
    hipMemsetAsync(d_out, 0x42, out_bytes, stream);

    if (n <= 0 || E <= 0 || n_in < 6) {
        hipMemsetAsync(d_out, 0x4E, out_bytes, stream);
        return;
    }

    size_t o_flags = 0;
    size_t o_degf = 256;
    size_t o_dinv = o_degf + (((size_t)n * 4 + 255) & ~(size_t)255);
    size_t o_h0 = o_dinv + (((size_t)n * 4 + 255) & ~(size_t)255);
    size_t o_h1 = o_h0 + (((size_t)n * HID * 4 + 255) & ~(size_t)255);
    size_t o_h2p = o_h1 + (((size_t)n * HID * 4 + 255) & ~(size_t)255);
    size_t o_h3p = o_h2p + (((size_t)n * HID * 4 + 255) & ~(size_t)255);
    size_t need = o_h3p + (((size_t)n * HID * 4 + 255) & ~(size_t)255);

    if (ws_size < need) {
        hipMemsetAsync(d_out, 0x4A, out_bytes, stream);  // ~3.2e6
        return;
    }

    char* p = (char*)d_ws;
    int* flags = (int*)(p + o_flags);
    float* degf = (float*)(p + o_degf);
    float* dinv = (float*)(p + o_dinv);
    float* h0 = (float*)(p + o_h0);
    float* h1 = (float*)(p + o_h1);
    float* h2p = (float*)(p + o_h2p);
    float* h3p = (float*)(p + o_h3p);

    int nb_h = (n * HID + 255) / 256;      // 16-wide passes
    int nb_e4 = (int)(((long long)E * 4 + 255) / 256);  // scatter16 grid

    k_probe<<<1, 256, 0, stream>>>(x, w1, eidx, E, flags);
    k_zero<<<nb_h, 256, 0, stream>>>(degf, h1, h3p, n);
    k_deg<<<(E + 255) / 256, 256, 0, stream>>>(eidx, flags, degf, E, n);
    k_dinv<<<(n + 255) / 256, 256, 0, stream>>>(degf, dinv, n);
    k_gemm1<<<nb_h, 256, 0, stream>>>(x, w1, flags, h0, n);
    k_scatter16<<<nb_e4, 256, 0, stream>>>(eidx, flags, dinv, h0, h1, E, n);
    k_relu<<<nb_h, 256, 0, stream>>>(h0, h1, dinv, b1, flags, h2p, n);
    k_scatter16<<<nb_e4, 256, 0, stream>>>(eidx, flags, dinv, h2p, h3p, E, n);
    k_check<<<1, 256, 0, stream>>>(eidx, h0, h3p, flags, E, n);
    SimplifiedGCN_5574867550498_kernel<<<nb_out, 256, 0, stream>>>(
        h2p, h3p, dinv, w2, b2, flags, out, n);
}

// Round 2
// 1225.318 us; speedup vs baseline: 1.6880x; 1.6880x over previous
//
#include <hip/hip_runtime.h>

typedef unsigned short u16;
typedef unsigned int u32;

#define FIN 512
#define HID 16
#define NCLS 64

// flags: [0]=edge-int64 [1]=x-fp32 [2]=weights-fp32 [3]=x-zero [4]=w1-zero
//        [8]=anomaly    [9]=anomaly code
__device__ __forceinline__ float bf2f_raw(u16 u) {
    u32 x = ((u32)u) << 16;
    float f; __builtin_memcpy(&f, &x, 4); return f;
}
// adaptive float load: element i of a logical float array stored fp32 or bf16
__device__ __forceinline__ float ldf(const void* p, long long i, int f32) {
    return f32 ? ((const float*)p)[i] : bf2f_raw(((const u16*)p)[i]);
}

// ---- probe raw bits of x, w1, edges; set flags ----
__global__ void k_probe(const void* x, const void* w1, const int* eidx, int E,
                        int* flags) {
    __shared__ int nz_x, nz_w, weird_x, weird_w, odd_nz;
    if (threadIdx.x == 0) { nz_x = 0; nz_w = 0; weird_x = 0; weird_w = 0; odd_nz = 0; }
    __syncthreads();
    const u16* xu = (const u16*)x;
    const u16* wu = (const u16*)w1;
    // "weird as bf16" = denormal or |v|>=2^65 — impossible for N(0,~1) data
    for (int i = threadIdx.x; i < 8192; i += 256) {
        u16 u = xu[i];
        if (u) atomicOr(&nz_x, 1);
        int e = (u >> 7) & 0xff;
        if ((e == 0 && (u & 0x7f)) || e >= 0xC0) atomicAdd(&weird_x, 1);
        u16 w = wu[i];
        if (w) atomicOr(&nz_w, 1);
        int ew = (w >> 7) & 0xff;
        if ((ew == 0 && (w & 0x7f)) || ew >= 0xC0) atomicAdd(&weird_w, 1);
    }
    // int64 little-endian nonneg < 2^31 => odd 32-bit words all zero
    int lim = (2 * E < 4096) ? 2 * E : 4096;
    for (int i = 1 + 2 * (int)threadIdx.x; i < lim; i += 512) {
        if (eidx[i] != 0) atomicOr(&odd_nz, 1);
    }
    __syncthreads();
    if (threadIdx.x == 0) {
        flags[0] = (odd_nz == 0) ? 1 : 0;
        flags[1] = (weird_x > 64) ? 1 : 0;
        flags[2] = (weird_w > 64) ? 1 : 0;
        flags[3] = (nz_x == 0) ? 1 : 0;
        flags[4] = (nz_w == 0) ? 1 : 0;
    }
}

__device__ __forceinline__ int ld_src(const int* eidx, int E, int e, int f64) {
    return f64 ? eidx[2LL * e] : eidx[e];
}
__device__ __forceinline__ int ld_dst(const int* eidx, int E, int e, int f64) {
    return f64 ? eidx[2LL * E + 2LL * e] : eidx[(long long)E + e];
}

__global__ void k_zero_deg(int* deg, int n) {
    int i = blockIdx.x * 256 + threadIdx.x;
    if (i < n) deg[i] = 0;
}

__global__ void k_count(const int* eidx, const int* flags, int* deg, int E, int n) {
    int e = blockIdx.x * 256 + threadIdx.x;
    if (e >= E) return;
    int d = ld_dst(eidx, E, e, flags[0]);
    if ((unsigned)d < (unsigned)n) atomicAdd(&deg[d], 1);
}

__global__ void k_dinv(const int* deg, float* dinv, int n) {
    int i = blockIdx.x * 256 + threadIdx.x;
    if (i < n) dinv[i] = rsqrtf((float)deg[i] + 1.0f);  // +1 self-loop
}

// ---- 3-kernel exclusive scan of deg -> row_start (and cursor copy) ----
__global__ void k_scan1(const int* deg, int* part, int n) {
    __shared__ int sd[256];
    int i = blockIdx.x * 256 + threadIdx.x;
    sd[threadIdx.x] = (i < n) ? deg[i] : 0;
    __syncthreads();
    for (int s = 128; s > 0; s >>= 1) {
        if (threadIdx.x < s) sd[threadIdx.x] += sd[threadIdx.x + s];
        __syncthreads();
    }
    if (threadIdx.x == 0) part[blockIdx.x] = sd[0];
}

// single block, 1024 threads: exclusive-scan part[], total -> row_start[n]
__global__ void k_scan2(int* part, int nparts, int* row_start, int n) {
    if (nparts > 1024) {  // fallback (never hit at n=100K)
        if (threadIdx.x == 0) {
            int acc = 0;
            for (int b = 0; b < nparts; b++) { int v = part[b]; part[b] = acc; acc += v; }
            row_start[n] = acc;
        }
        return;
    }
    __shared__ int sd[1024];
    int t = threadIdx.x;
    int v = (t < nparts) ? part[t] : 0;
    sd[t] = v;
    __syncthreads();
    for (int s = 1; s < 1024; s <<= 1) {
        int u = (t >= s) ? sd[t - s] : 0;
        __syncthreads();
        sd[t] += u;
        __syncthreads();
    }
    if (t < nparts) part[t] = sd[t] - v;  // exclusive
    if (t == 0) row_start[n] = sd[1023];  // grand total
}

__global__ void k_scan3(const int* deg, const int* part, int* row_start,
                        int* cursor, int n) {
    __shared__ int sd[256];
    int i = blockIdx.x * 256 + threadIdx.x;
    int v = (i < n) ? deg[i] : 0;
    sd[threadIdx.x] = v;
    __syncthreads();
    for (int s = 1; s < 256; s <<= 1) {
        int u = (threadIdx.x >= s) ? sd[threadIdx.x - s] : 0;
        __syncthreads();
        sd[threadIdx.x] += u;
        __syncthreads();
    }
    if (i < n) {
        int ex = sd[threadIdx.x] - v + part[blockIdx.x];
        row_start[i] = ex;
        cursor[i] = ex;
    }
}

// bucket src indices by dst (atomic ticket); order within bucket irrelevant
__global__ void k_fill(const int* eidx, const int* flags, int* cursor, int* csr,
                       int E, int n) {
    int e = blockIdx.x * 256 + threadIdx.x;
    if (e >= E) return;
    int f64 = flags[0];
    int s = ld_src(eidx, E, e, f64);
    int d = ld_dst(eidx, E, e, f64);
    if ((unsigned)d >= (unsigned)n) return;
    int slot = atomicAdd(&cursor[d], 1);
    csr[slot] = ((unsigned)s < (unsigned)n) ? s : -1;
}

// h0s[n,16] = dinv[node] * (x[n,512] @ W1[512,16])  (pre-scaled by dinv)
__global__ void k_gemm1(const void* x, const void* w1, const int* flags,
                        const float* dinv, float* h0s, int n) {
    int t = blockIdx.x * 256 + threadIdx.x;
    if (t >= n * HID) return;
    int node = t >> 4;
    int f = t & 15;
    int fx = flags[1], fw = flags[2];
    long long xb = (long long)node * FIN;
    float acc = 0.0f;
    for (int k = 0; k < FIN; k++) {
        acc += ldf(x, xb + k, fx) * ldf(w1, (long long)k * HID + f, fw);
    }
    h0s[t] = dinv[node] * acc;
}

// gather propagation over pre-scaled features (h_in = dinv.*h):
//   acc = h_in[d] (self-loop) + sum_{s in N(d)} h_in[s]
//   RELU=1: h_out = dinv[d] * relu(dinv[d]*acc + b1)   (pre-scaled for layer 2)
//   RELU=0: h_out = dinv[d] * acc                       (final propagated hidden)
template <int RELU>
__global__ void k_gather(const int* row_start, const int* csr, const float* dinv,
                         const float* h_in, const void* b, const int* flags,
                         float* h_out, int n) {
    int t = blockIdx.x * 256 + threadIdx.x;
    if (t >= n * HID) return;
    int d = t >> 4;
    int f = t & 15;
    int beg = row_start[d], end = row_start[d + 1];
    float acc = h_in[d * HID + f];  // self-loop (pre-scaled)
    for (int i = beg; i < end; i++) {
        int s = csr[i];
        if (s >= 0) acc += h_in[s * HID + f];
    }
    float di = dinv[d];
    if (RELU) {
        float v = di * acc + ldf(b, f, flags[2]);
        h_out[t] = di * fmaxf(v, 0.0f);
    } else {
        h_out[t] = di * acc;
    }
}

// ---- post-pipeline anomaly check; beacon only when something is wrong ----
__global__ void k_check(const int* eidx, const float* h0s, const float* g,
                        int* flags, int E, int n) {
    __shared__ int h0nz, gnz, dstz;
    if (threadIdx.x == 0) { h0nz = 0; gnz = 0; dstz = 0; }
    __syncthreads();
    for (int i = threadIdx.x; i < 4096; i += 256) {
        if (h0s[i] != 0.0f) atomicOr(&h0nz, 1);
        if (g[i] != 0.0f) atomicOr(&gnz, 1);
    }
    int f64 = flags[0];
    for (int e = threadIdx.x; e < 2048; e += 256) {
        if (ld_dst(eidx, E, e, f64) == 0) atomicAdd(&dstz, 1);
    }
    __syncthreads();
    if (threadIdx.x == 0) {
        int b0 = flags[3];             // x sample all zero
        int b1 = flags[4];             // w1 sample all zero
        int b2 = (dstz > 102);         // >5% of dst sample == 0 (edge misread)
        int b3 = (h0nz == 0);          // gemm1 produced nothing
        int b4 = (gnz == 0);           // propagation produced nothing
        int b5 = flags[1];             // info: x fp32
        int b6 = flags[2];             // info: weights fp32
        int b7 = flags[0];             // info: edges int64
        flags[9] = b0 | (b1 << 1) | (b2 << 2) | (b3 << 3) | (b4 << 4) |
                   (b5 << 5) | (b6 << 6) | (b7 << 7);
        flags[8] = (b0 | b1 | b2 | b3 | b4) ? 1 : 0;
    }
}

// out[n,64] = g[n,16] @ W2[16,64] + b2
__global__ void SimplifiedGCN_5574867550498_kernel(
        const float* g, const void* w2, const void* b2, const int* flags,
        float* out, int n) {
    int t = blockIdx.x * 256 + threadIdx.x;
    if (t >= n * NCLS) return;
    int node = t >> 6;
    int c = t & 63;
    int fw = flags[2];
    float acc = ldf(b2, c, fw);
    for (int k = 0; k < HID; k++) {
        acc += g[node * HID + k] * ldf(w2, (long long)k * NCLS + c, fw);
    }
    if (t == 0 && flags[8]) acc = 4096.0f + 2.0f * (float)flags[9];  // beacon
    out[t] = acc;
}

extern "C" void kernel_launch(void* const* d_in, const int* in_sizes, int n_in,
                              void* d_out, int out_size, void* d_ws, size_t ws_size,
                              hipStream_t stream) {
    const void* x = d_in[0];
    const int* eidx = (const int*)d_in[1];
    const void* w1 = d_in[2];
    const void* b1 = d_in[3];
    const void* w2 = d_in[4];
    const void* b2 = d_in[5];
    float* out = (float*)d_out;

    int n = in_sizes[0] / FIN;
    int E = in_sizes[1] / 2;
    int total_out = n * NCLS;
    int nb_out = (total_out + 255) / 256;
    size_t out_bytes = (size_t)total_out * 4;

    // ~48.5 everywhere if later kernels never write
    hipMemsetAsync(d_out, 0x42, out_bytes, stream);

    if (n <= 0 || E <= 0 || n_in < 6) {
        hipMemsetAsync(d_out, 0x4E, out_bytes, stream);
        return;
    }

    int nb_n = (n + 255) / 256;        // per-node grids; also nparts for scan
    int nparts = nb_n;

    size_t A = 255;  // align helper
    size_t o_flags = 0;
    size_t o_deg   = 256;
    size_t o_dinv  = o_deg   + (((size_t)n * 4 + A) & ~A);
    size_t o_rs    = o_dinv  + (((size_t)n * 4 + A) & ~A);
    size_t o_part  = o_rs    + (((size_t)(n + 1) * 4 + A) & ~A);
    size_t o_cur   = o_part  + (((size_t)nparts * 4 + A) & ~A);
    size_t o_h0s   = o_cur   + (((size_t)n * 4 + A) & ~A);
    size_t o_h2ps  = o_h0s   + (((size_t)n * HID * 4 + A) & ~A);
    size_t o_g     = o_h2ps  + (((size_t)n * HID * 4 + A) & ~A);
    size_t o_csr   = o_g     + (((size_t)n * HID * 4 + A) & ~A);
    size_t need    = o_csr   + (((size_t)E * 4 + A) & ~A);

    if (ws_size < need) {
        hipMemsetAsync(d_out, 0x4A, out_bytes, stream);  // ~3.2e6
        return;
    }

    char* p = (char*)d_ws;
    int* flags      = (int*)(p + o_flags);
    int* deg        = (int*)(p + o_deg);
    float* dinv     = (float*)(p + o_dinv);
    int* row_start  = (int*)(p + o_rs);
    int* part       = (int*)(p + o_part);
    int* cursor     = (int*)(p + o_cur);
    float* h0s      = (float*)(p + o_h0s);
    float* h2ps     = (float*)(p + o_h2ps);
    float* g        = (float*)(p + o_g);
    int* csr        = (int*)(p + o_csr);

    int nb_e = (E + 255) / 256;
    int nb_h = (n * HID + 255) / 256;

    k_probe<<<1, 256, 0, stream>>>(x, w1, eidx, E, flags);
    k_zero_deg<<<nb_n, 256, 0, stream>>>(deg, n);
    k_count<<<nb_e, 256, 0, stream>>>(eidx, flags, deg, E, n);
    k_dinv<<<nb_n, 256, 0, stream>>>(deg, dinv, n);
    k_scan1<<<nb_n, 256, 0, stream>>>(deg, part, n);
    k_scan2<<<1, 1024, 0, stream>>>(part, nparts, row_start, n);
    k_scan3<<<nb_n, 256, 0, stream>>>(deg, part, row_start, cursor, n);
    k_fill<<<nb_e, 256, 0, stream>>>(eidx, flags, cursor, csr, E, n);
    k_gemm1<<<nb_h, 256, 0, stream>>>(x, w1, flags, dinv, h0s, n);
    k_gather<1><<<nb_h, 256, 0, stream>>>(row_start, csr, dinv, h0s, b1, flags,
                                          h2ps, n);
    k_gather<0><<<nb_h, 256, 0, stream>>>(row_start, csr, dinv, h2ps, b1, flags,
                                          g, n);
    k_check<<<1, 256, 0, stream>>>(eidx, h0s, g, flags, E, n);
    SimplifiedGCN_5574867550498_kernel<<<nb_out, 256, 0, stream>>>(
        g, w2, b2, flags, out, n);
}

// Round 3
// 906.564 us; speedup vs baseline: 2.2816x; 1.3516x over previous
//
#include <hip/hip_runtime.h>

typedef unsigned short u16;
typedef unsigned int u32;

#define FIN 512
#define HID 16
#define NCLS 64

typedef __bf16 bf16x8 __attribute__((ext_vector_type(8)));
typedef float f32x4 __attribute__((ext_vector_type(4)));

// flags: [0]=edge-int64 [1]=x-fp32 [2]=weights-fp32 [3]=x-zero [4]=w1-zero
//        [8]=anomaly    [9]=anomaly code
__device__ __forceinline__ float bf2f_raw(u16 u) {
    u32 x = ((u32)u) << 16;
    float f; __builtin_memcpy(&f, &x, 4); return f;
}
// adaptive float load: element i of a logical float array stored fp32 or bf16
__device__ __forceinline__ float ldf(const void* p, long long i, int f32) {
    return f32 ? ((const float*)p)[i] : bf2f_raw(((const u16*)p)[i]);
}
__device__ __forceinline__ u16 f2bf_trunc(float v) {
    u32 bits; __builtin_memcpy(&bits, &v, 4);
    return (u16)(bits >> 16);
}

// ---- probe raw bits of x, w1, edges; set flags ----
__global__ void k_probe(const void* x, const void* w1, const int* eidx, int E,
                        int* flags) {
    __shared__ int nz_x, nz_w, weird_x, weird_w, odd_nz;
    if (threadIdx.x == 0) { nz_x = 0; nz_w = 0; weird_x = 0; weird_w = 0; odd_nz = 0; }
    __syncthreads();
    const u16* xu = (const u16*)x;
    const u16* wu = (const u16*)w1;
    // "weird as bf16" = denormal or |v|>=2^65 — impossible for N(0,~1) data
    for (int i = threadIdx.x; i < 8192; i += 256) {
        u16 u = xu[i];
        if (u) atomicOr(&nz_x, 1);
        int e = (u >> 7) & 0xff;
        if ((e == 0 && (u & 0x7f)) || e >= 0xC0) atomicAdd(&weird_x, 1);
        u16 w = wu[i];
        if (w) atomicOr(&nz_w, 1);
        int ew = (w >> 7) & 0xff;
        if ((ew == 0 && (w & 0x7f)) || ew >= 0xC0) atomicAdd(&weird_w, 1);
    }
    // int64 little-endian nonneg < 2^31 => odd 32-bit words all zero
    int lim = (2 * E < 4096) ? 2 * E : 4096;
    for (int i = 1 + 2 * (int)threadIdx.x; i < lim; i += 512) {
        if (eidx[i] != 0) atomicOr(&odd_nz, 1);
    }
    __syncthreads();
    if (threadIdx.x == 0) {
        flags[0] = (odd_nz == 0) ? 1 : 0;
        flags[1] = (weird_x > 64) ? 1 : 0;
        flags[2] = (weird_w > 64) ? 1 : 0;
        flags[3] = (nz_x == 0) ? 1 : 0;
        flags[4] = (nz_w == 0) ? 1 : 0;
    }
}

__device__ __forceinline__ int ld_src(const int* eidx, int E, int e, int f64) {
    return f64 ? eidx[2LL * e] : eidx[e];
}
__device__ __forceinline__ int ld_dst(const int* eidx, int E, int e, int f64) {
    return f64 ? eidx[2LL * E + 2LL * e] : eidx[(long long)E + e];
}

__global__ void k_zero_deg(int* deg, int n) {
    int i = blockIdx.x * 256 + threadIdx.x;
    if (i < n) deg[i] = 0;
}

__global__ void k_count(const int* eidx, const int* flags, int* deg, int E, int n) {
    int e = blockIdx.x * 256 + threadIdx.x;
    if (e >= E) return;
    int d = ld_dst(eidx, E, e, flags[0]);
    if ((unsigned)d < (unsigned)n) atomicAdd(&deg[d], 1);
}

__global__ void k_dinv(const int* deg, float* dinv, int n) {
    int i = blockIdx.x * 256 + threadIdx.x;
    if (i < n) dinv[i] = rsqrtf((float)deg[i] + 1.0f);  // +1 self-loop
}

// ---- 3-kernel exclusive scan of deg -> row_start (and cursor copy) ----
__global__ void k_scan1(const int* deg, int* part, int n) {
    __shared__ int sd[256];
    int i = blockIdx.x * 256 + threadIdx.x;
    sd[threadIdx.x] = (i < n) ? deg[i] : 0;
    __syncthreads();
    for (int s = 128; s > 0; s >>= 1) {
        if (threadIdx.x < s) sd[threadIdx.x] += sd[threadIdx.x + s];
        __syncthreads();
    }
    if (threadIdx.x == 0) part[blockIdx.x] = sd[0];
}

// single block, 1024 threads: exclusive-scan part[], total -> row_start[n]
__global__ void k_scan2(int* part, int nparts, int* row_start, int n) {
    if (nparts > 1024) {  // fallback (never hit at n=100K)
        if (threadIdx.x == 0) {
            int acc = 0;
            for (int b = 0; b < nparts; b++) { int v = part[b]; part[b] = acc; acc += v; }
            row_start[n] = acc;
        }
        return;
    }
    __shared__ int sd[1024];
    int t = threadIdx.x;
    int v = (t < nparts) ? part[t] : 0;
    sd[t] = v;
    __syncthreads();
    for (int s = 1; s < 1024; s <<= 1) {
        int u = (t >= s) ? sd[t - s] : 0;
        __syncthreads();
        sd[t] += u;
        __syncthreads();
    }
    if (t < nparts) part[t] = sd[t] - v;  // exclusive
    if (t == 0) row_start[n] = sd[1023];  // grand total
}

__global__ void k_scan3(const int* deg, const int* part, int* row_start,
                        int* cursor, int n) {
    __shared__ int sd[256];
    int i = blockIdx.x * 256 + threadIdx.x;
    int v = (i < n) ? deg[i] : 0;
    sd[threadIdx.x] = v;
    __syncthreads();
    for (int s = 1; s < 256; s <<= 1) {
        int u = (threadIdx.x >= s) ? sd[threadIdx.x - s] : 0;
        __syncthreads();
        sd[threadIdx.x] += u;
        __syncthreads();
    }
    if (i < n) {
        int ex = sd[threadIdx.x] - v + part[blockIdx.x];
        row_start[i] = ex;
        cursor[i] = ex;
    }
}

// bucket src indices by dst (atomic ticket); order within bucket irrelevant
__global__ void k_fill(const int* eidx, const int* flags, int* cursor, int* csr,
                       int E, int n) {
    int e = blockIdx.x * 256 + threadIdx.x;
    if (e >= E) return;
    int f64 = flags[0];
    int s = ld_src(eidx, E, e, f64);
    int d = ld_dst(eidx, E, e, f64);
    if ((unsigned)d >= (unsigned)n) return;
    int slot = atomicAdd(&cursor[d], 1);
    csr[slot] = ((unsigned)s < (unsigned)n) ? s : -1;
}

// h0s[n,16] = dinv[node] * (x[n,512] @ W1[512,16])  via MFMA 16x16x32 bf16
// A-frag: lane holds x[base+(l&15)][kb + (l>>4)*8 .. +7] (bf16x8, 16B load)
// B-frag: W1^T staged in LDS ([16][512] bf16, XOR-swizzled), contiguous-8 read
// C-frag: col(=feature)=l&15, row(=node)=(l>>4)*4+reg  [m89-verified mapping]
__global__ void __launch_bounds__(256)
k_gemm1(const void* x, const void* w1, const int* flags, const float* dinv,
        float* h0s, int n) {
    __shared__ __attribute__((aligned(16))) u16 w1t[16 * 512];
    int tid = threadIdx.x;
    int fx = flags[1], fw = flags[2];
    // stage W1^T (convert to bf16; identity bits if already bf16), swizzled:
    // u16 index = (f<<9 | k) ^ ((f&7)<<3)  — breaks the stride-1024B bank wall
    for (int i = tid; i < 8192; i += 256) {
        int k = i >> 4, f = i & 15;
        float v = ldf(w1, (long long)k * HID + f, fw);
        int idx = ((f << 9) + k) ^ ((f & 7) << 3);
        w1t[idx] = f2bf_trunc(v);
    }
    __syncthreads();

    int wave = tid >> 6;
    int lane = tid & 63;
    int base = blockIdx.x * 64 + wave * 16;
    if (base >= n) return;
    int rowA = base + (lane & 15);
    if (rowA >= n) rowA = n - 1;          // clamp; OOB rows never stored
    int g = lane >> 4;                     // k-group 0..3
    int nn = lane & 15;
    f32x4 acc = {0.0f, 0.0f, 0.0f, 0.0f};

    if (!fx) {  // bf16 x: direct 16B fragment loads (the real path)
        const u16* xp = (const u16*)x + (long long)rowA * FIN + g * 8;
        #pragma unroll
        for (int kb = 0; kb < FIN; kb += 32) {
            bf16x8 a = *(const bf16x8*)(xp + kb);
            int bidx = ((nn << 9) + kb + g * 8) ^ ((nn & 7) << 3);
            bf16x8 b = *(const bf16x8*)(w1t + bidx);
            acc = __builtin_amdgcn_mfma_f32_16x16x32_bf16(a, b, acc, 0, 0, 0);
        }
    } else {    // fp32 x: convert on the fly (defensive path)
        const float* xp = (const float*)x + (long long)rowA * FIN + g * 8;
        #pragma unroll 4
        for (int kb = 0; kb < FIN; kb += 32) {
            float vf[8];
            *(float4*)(vf) = *(const float4*)(xp + kb);
            *(float4*)(vf + 4) = *(const float4*)(xp + kb + 4);
            bf16x8 a;
            #pragma unroll
            for (int j = 0; j < 8; j++) ((u16*)&a)[j] = f2bf_trunc(vf[j]);
            int bidx = ((nn << 9) + kb + g * 8) ^ ((nn & 7) << 3);
            bf16x8 b = *(const bf16x8*)(w1t + bidx);
            acc = __builtin_amdgcn_mfma_f32_16x16x32_bf16(a, b, acc, 0, 0, 0);
        }
    }
    #pragma unroll
    for (int r = 0; r < 4; r++) {
        int node = base + g * 4 + r;
        if (node < n) h0s[node * HID + nn] = acc[r] * dinv[node];
    }
}

// gather propagation over pre-scaled features (h_in = dinv.*h), float4-wide:
//   acc = h_in[d] (self-loop) + sum_{s in N(d)} h_in[s]
//   RELU=1: h_out = dinv[d] * relu(dinv[d]*acc + b1)   (pre-scaled for layer 2)
//   RELU=0: h_out = dinv[d] * acc                       (final propagated hidden)
template <int RELU>
__global__ void k_gather(const int* row_start, const int* csr, const float* dinv,
                         const float* h_in, const void* b, const int* flags,
                         float* h_out, int n) {
    int t = blockIdx.x * 256 + threadIdx.x;
    if (t >= n * 4) return;
    int d = t >> 2;
    int g = t & 3;
    int beg = row_start[d], end = row_start[d + 1];
    const float4* hv = (const float4*)h_in;
    float4 acc = hv[d * 4 + g];  // self-loop (pre-scaled)
    for (int i = beg; i < end; i++) {
        int s = csr[i];
        if (s >= 0) {
            float4 v = hv[s * 4 + g];
            acc.x += v.x; acc.y += v.y; acc.z += v.z; acc.w += v.w;
        }
    }
    float di = dinv[d];
    float4 o;
    if (RELU) {
        int fw = flags[2];
        o.x = di * fmaxf(di * acc.x + ldf(b, g * 4 + 0, fw), 0.0f);
        o.y = di * fmaxf(di * acc.y + ldf(b, g * 4 + 1, fw), 0.0f);
        o.z = di * fmaxf(di * acc.z + ldf(b, g * 4 + 2, fw), 0.0f);
        o.w = di * fmaxf(di * acc.w + ldf(b, g * 4 + 3, fw), 0.0f);
    } else {
        o.x = di * acc.x; o.y = di * acc.y; o.z = di * acc.z; o.w = di * acc.w;
    }
    ((float4*)h_out)[t] = o;
}

// ---- post-pipeline anomaly check; beacon only when something is wrong ----
__global__ void k_check(const int* eidx, const float* h0s, const float* g,
                        int* flags, int E, int n) {
    __shared__ int h0nz, gnz, dstz;
    if (threadIdx.x == 0) { h0nz = 0; gnz = 0; dstz = 0; }
    __syncthreads();
    for (int i = threadIdx.x; i < 4096; i += 256) {
        if (h0s[i] != 0.0f) atomicOr(&h0nz, 1);
        if (g[i] != 0.0f) atomicOr(&gnz, 1);
    }
    int f64 = flags[0];
    for (int e = threadIdx.x; e < 2048; e += 256) {
        if (ld_dst(eidx, E, e, f64) == 0) atomicAdd(&dstz, 1);
    }
    __syncthreads();
    if (threadIdx.x == 0) {
        int b0 = flags[3];             // x sample all zero
        int b1 = flags[4];             // w1 sample all zero
        int b2 = (dstz > 102);         // >5% of dst sample == 0 (edge misread)
        int b3 = (h0nz == 0);          // gemm1 produced nothing
        int b4 = (gnz == 0);           // propagation produced nothing
        int b5 = flags[1];             // info: x fp32
        int b6 = flags[2];             // info: weights fp32
        int b7 = flags[0];             // info: edges int64
        flags[9] = b0 | (b1 << 1) | (b2 << 2) | (b3 << 3) | (b4 << 4) |
                   (b5 << 5) | (b6 << 6) | (b7 << 7);
        flags[8] = (b0 | b1 | b2 | b3 | b4) ? 1 : 0;
    }
}

// out[n,64] = g[n,16] @ W2[16,64] + b2
__global__ void SimplifiedGCN_5574867550498_kernel(
        const float* g, const void* w2, const void* b2, const int* flags,
        float* out, int n) {
    int t = blockIdx.x * 256 + threadIdx.x;
    if (t >= n * NCLS) return;
    int node = t >> 6;
    int c = t & 63;
    int fw = flags[2];
    float acc = ldf(b2, c, fw);
    for (int k = 0; k < HID; k++) {
        acc += g[node * HID + k] * ldf(w2, (long long)k * NCLS + c, fw);
    }
    if (t == 0 && flags[8]) acc = 4096.0f + 2.0f * (float)flags[9];  // beacon
    out[t] = acc;
}

extern "C" void kernel_launch(void* const* d_in, const int* in_sizes, int n_in,
                              void* d_out, int out_size, void* d_ws, size_t ws_size,
                              hipStream_t stream) {
    const void* x = d_in[0];
    const int* eidx = (const int*)d_in[1];
    const void* w1 = d_in[2];
    const void* b1 = d_in[3];
    const void* w2 = d_in[4];
    const void* b2 = d_in[5];
    float* out = (float*)d_out;

    int n = in_sizes[0] / FIN;
    int E = in_sizes[1] / 2;
    int total_out = n * NCLS;
    int nb_out = (total_out + 255) / 256;
    size_t out_bytes = (size_t)total_out * 4;

    // ~48.5 everywhere if later kernels never write
    hipMemsetAsync(d_out, 0x42, out_bytes, stream);

    if (n <= 0 || E <= 0 || n_in < 6) {
        hipMemsetAsync(d_out, 0x4E, out_bytes, stream);
        return;
    }

    int nb_n = (n + 255) / 256;        // per-node grids; also nparts for scan
    int nparts = nb_n;

    size_t A = 255;  // align helper
    size_t o_flags = 0;
    size_t o_deg   = 256;
    size_t o_dinv  = o_deg   + (((size_t)n * 4 + A) & ~A);
    size_t o_rs    = o_dinv  + (((size_t)n * 4 + A) & ~A);
    size_t o_part  = o_rs    + (((size_t)(n + 1) * 4 + A) & ~A);
    size_t o_cur   = o_part  + (((size_t)nparts * 4 + A) & ~A);
    size_t o_h0s   = o_cur   + (((size_t)n * 4 + A) & ~A);
    size_t o_h2ps  = o_h0s   + (((size_t)n * HID * 4 + A) & ~A);
    size_t o_g     = o_h2ps  + (((size_t)n * HID * 4 + A) & ~A);
    size_t o_csr   = o_g     + (((size_t)n * HID * 4 + A) & ~A);
    size_t need    = o_csr   + (((size_t)E * 4 + A) & ~A);

    if (ws_size < need) {
        hipMemsetAsync(d_out, 0x4A, out_bytes, stream);  // ~3.2e6
        return;
    }

    char* p = (char*)d_ws;
    int* flags      = (int*)(p + o_flags);
    int* deg        = (int*)(p + o_deg);
    float* dinv     = (float*)(p + o_dinv);
    int* row_start  = (int*)(p + o_rs);
    int* part       = (int*)(p + o_part);
    int* cursor     = (int*)(p + o_cur);
    float* h0s      = (float*)(p + o_h0s);
    float* h2ps     = (float*)(p + o_h2ps);
    float* g        = (float*)(p + o_g);
    int* csr        = (int*)(p + o_csr);

    int nb_e = (E + 255) / 256;
    int nb_g1 = (n + 63) / 64;             // 64 nodes per gemm1 block
    int nb_h4 = (n * 4 + 255) / 256;       // float4-wide gather grid

    k_probe<<<1, 256, 0, stream>>>(x, w1, eidx, E, flags);
    k_zero_deg<<<nb_n, 256, 0, stream>>>(deg, n);
    k_count<<<nb_e, 256, 0, stream>>>(eidx, flags, deg, E, n);
    k_dinv<<<nb_n, 256, 0, stream>>>(deg, dinv, n);
    k_scan1<<<nb_n, 256, 0, stream>>>(deg, part, n);
    k_scan2<<<1, 1024, 0, stream>>>(part, nparts, row_start, n);
    k_scan3<<<nb_n, 256, 0, stream>>>(deg, part, row_start, cursor, n);
    k_fill<<<nb_e, 256, 0, stream>>>(eidx, flags, cursor, csr, E, n);
    k_gemm1<<<nb_g1, 256, 0, stream>>>(x, w1, flags, dinv, h0s, n);
    k_gather<1><<<nb_h4, 256, 0, stream>>>(row_start, csr, dinv, h0s, b1, flags,
                                           h2ps, n);
    k_gather<0><<<nb_h4, 256, 0, stream>>>(row_start, csr, dinv, h2ps, b1, flags,
                                           g, n);
    k_check<<<1, 256, 0, stream>>>(eidx, h0s, g, flags, E, n);
    SimplifiedGCN_5574867550498_kernel<<<nb_out, 256, 0, stream>>>(
        g, w2, b2, flags, out, n);
}

// Round 4
// 775.615 us; speedup vs baseline: 2.6668x; 1.1688x over previous
//
#include <hip/hip_runtime.h>

typedef unsigned short u16;
typedef unsigned int u32;

#define FIN 512
#define HID 16
#define NCLS 64

typedef __bf16 bf16x8 __attribute__((ext_vector_type(8)));
typedef float f32x4 __attribute__((ext_vector_type(4)));

// flags: [0]=edge-int64 [1]=x-fp32 [2]=weights-fp32 [3]=x-zero [4]=w1-zero
//        [8]=anomaly    [9]=anomaly code
__device__ __forceinline__ float bf2f_raw(u16 u) {
    u32 x = ((u32)u) << 16;
    float f; __builtin_memcpy(&f, &x, 4); return f;
}
// adaptive float load: element i of a logical float array stored fp32 or bf16
__device__ __forceinline__ float ldf(const void* p, long long i, int f32) {
    return f32 ? ((const float*)p)[i] : bf2f_raw(((const u16*)p)[i]);
}
__device__ __forceinline__ u16 f2bf_rne(float v) {
    u32 bits; __builtin_memcpy(&bits, &v, 4);
    u32 lsb = (bits >> 16) & 1;
    bits += 0x7FFFu + lsb;           // round-to-nearest-even
    return (u16)(bits >> 16);
}

// ---- probe raw bits of x, w1, edges; set flags ----
__global__ void k_probe(const void* x, const void* w1, const int* eidx, int E,
                        int* flags) {
    __shared__ int nz_x, nz_w, weird_x, weird_w, odd_nz;
    if (threadIdx.x == 0) { nz_x = 0; nz_w = 0; weird_x = 0; weird_w = 0; odd_nz = 0; }
    __syncthreads();
    const u16* xu = (const u16*)x;
    const u16* wu = (const u16*)w1;
    // "weird as bf16" = denormal or |v|>=2^65 — impossible for N(0,~1) data
    for (int i = threadIdx.x; i < 8192; i += 256) {
        u16 u = xu[i];
        if (u) atomicOr(&nz_x, 1);
        int e = (u >> 7) & 0xff;
        if ((e == 0 && (u & 0x7f)) || e >= 0xC0) atomicAdd(&weird_x, 1);
        u16 w = wu[i];
        if (w) atomicOr(&nz_w, 1);
        int ew = (w >> 7) & 0xff;
        if ((ew == 0 && (w & 0x7f)) || ew >= 0xC0) atomicAdd(&weird_w, 1);
    }
    // int64 little-endian nonneg < 2^31 => odd 32-bit words all zero
    int lim = (2 * E < 4096) ? 2 * E : 4096;
    for (int i = 1 + 2 * (int)threadIdx.x; i < lim; i += 512) {
        if (eidx[i] != 0) atomicOr(&odd_nz, 1);
    }
    __syncthreads();
    if (threadIdx.x == 0) {
        flags[0] = (odd_nz == 0) ? 1 : 0;
        flags[1] = (weird_x > 64) ? 1 : 0;
        flags[2] = (weird_w > 64) ? 1 : 0;
        flags[3] = (nz_x == 0) ? 1 : 0;
        flags[4] = (nz_w == 0) ? 1 : 0;
    }
}

__device__ __forceinline__ int ld_src(const int* eidx, int E, int e, int f64) {
    return f64 ? eidx[2LL * e] : eidx[e];
}
__device__ __forceinline__ int ld_dst(const int* eidx, int E, int e, int f64) {
    return f64 ? eidx[2LL * E + 2LL * e] : eidx[(long long)E + e];
}

__global__ void k_count(const int* eidx, const int* flags, int* deg, int E, int n) {
    int e = blockIdx.x * 256 + threadIdx.x;
    if (e >= E) return;
    int d = ld_dst(eidx, E, e, flags[0]);
    if ((unsigned)d < (unsigned)n) atomicAdd(&deg[d], 1);
}

__global__ void k_dinv(const int* deg, float* dinv, int n) {
    int i = blockIdx.x * 256 + threadIdx.x;
    if (i < n) dinv[i] = rsqrtf((float)deg[i] + 1.0f);  // +1 self-loop
}

// ---- 3-kernel exclusive scan of deg -> row_start (and cursor copy) ----
__global__ void k_scan1(const int* deg, int* part, int n) {
    __shared__ int sd[256];
    int i = blockIdx.x * 256 + threadIdx.x;
    sd[threadIdx.x] = (i < n) ? deg[i] : 0;
    __syncthreads();
    for (int s = 128; s > 0; s >>= 1) {
        if (threadIdx.x < s) sd[threadIdx.x] += sd[threadIdx.x + s];
        __syncthreads();
    }
    if (threadIdx.x == 0) part[blockIdx.x] = sd[0];
}

// single block, 1024 threads: exclusive-scan part[], total -> row_start[n]
__global__ void k_scan2(int* part, int nparts, int* row_start, int n) {
    if (nparts > 1024) {  // fallback (never hit at n=100K)
        if (threadIdx.x == 0) {
            int acc = 0;
            for (int b = 0; b < nparts; b++) { int v = part[b]; part[b] = acc; acc += v; }
            row_start[n] = acc;
        }
        return;
    }
    __shared__ int sd[1024];
    int t = threadIdx.x;
    int v = (t < nparts) ? part[t] : 0;
    sd[t] = v;
    __syncthreads();
    for (int s = 1; s < 1024; s <<= 1) {
        int u = (t >= s) ? sd[t - s] : 0;
        __syncthreads();
        sd[t] += u;
        __syncthreads();
    }
    if (t < nparts) part[t] = sd[t] - v;  // exclusive
    if (t == 0) row_start[n] = sd[1023];  // grand total
}

__global__ void k_scan3(const int* deg, const int* part, int* row_start,
                        int* cursor, int n) {
    __shared__ int sd[256];
    int i = blockIdx.x * 256 + threadIdx.x;
    int v = (i < n) ? deg[i] : 0;
    sd[threadIdx.x] = v;
    __syncthreads();
    for (int s = 1; s < 256; s <<= 1) {
        int u = (threadIdx.x >= s) ? sd[threadIdx.x - s] : 0;
        __syncthreads();
        sd[threadIdx.x] += u;
        __syncthreads();
    }
    if (i < n) {
        int ex = sd[threadIdx.x] - v + part[blockIdx.x];
        row_start[i] = ex;
        cursor[i] = ex;
    }
}

// bucket src by dst, XCD-range-partitioned: block bid handles dst range
// (bid&7) — one range per XCD under the default %8 round-robin mapping —
// and edge chunk (bid>>3). Each XCD's csr writes stay in its own contiguous
// ~1.6MB slice => 16 writes/line, L2-resident, writeback ~12.8MB (was 195MB).
__global__ void k_fill(const int* eidx, const int* flags, int* cursor, int* csr,
                       int E, int n, int nchunk) {
    int r = blockIdx.x & 7;
    int cblk = blockIdx.x >> 3;
    int lo = (int)(((long long)r * n) >> 3);
    int hi = (int)(((long long)(r + 1) * n) >> 3);
    int f64 = flags[0];
    long long stride = (long long)nchunk * 256;
    for (long long e = (long long)cblk * 256 + threadIdx.x; e < E; e += stride) {
        int d = ld_dst(eidx, E, (int)e, f64);
        if (d < lo || d >= hi) continue;  // drops OOB too (d<0 or d>=n)
        int s = ld_src(eidx, E, (int)e, f64);
        int slot = atomicAdd(&cursor[d], 1);
        csr[slot] = ((unsigned)s < (unsigned)n) ? s : -1;
    }
}

// h0s[n,16] = dinv[node] * (x[n,512] @ W1[512,16])  via MFMA 16x16x32 bf16
// A-frag: lane holds x[base+(l&15)][kb + (l>>4)*8 .. +7] (bf16x8, 16B load)
// B-frag: W1^T staged in LDS ([16][512] bf16, XOR-swizzled), contiguous-8 read
// C-frag: col(=feature)=l&15, row(=node)=(l>>4)*4+reg  [m89-verified mapping]
__global__ void __launch_bounds__(256)
k_gemm1(const void* x, const void* w1, const int* flags, const float* dinv,
        float* h0s, int n) {
    __shared__ __attribute__((aligned(16))) u16 w1t[16 * 512];
    int tid = threadIdx.x;
    int fx = flags[1], fw = flags[2];
    // stage W1^T (convert to bf16; identity bits if already bf16), swizzled:
    // u16 index = (f<<9 | k) ^ ((f&7)<<3)  — breaks the stride-1024B bank wall
    for (int i = tid; i < 8192; i += 256) {
        int k = i >> 4, f = i & 15;
        float v = ldf(w1, (long long)k * HID + f, fw);
        int idx = ((f << 9) + k) ^ ((f & 7) << 3);
        w1t[idx] = f2bf_rne(v);
    }
    __syncthreads();

    int wave = tid >> 6;
    int lane = tid & 63;
    int base = blockIdx.x * 64 + wave * 16;
    if (base >= n) return;
    int rowA = base + (lane & 15);
    if (rowA >= n) rowA = n - 1;          // clamp; OOB rows never stored
    int g = lane >> 4;                     // k-group 0..3
    int nn = lane & 15;
    f32x4 acc = {0.0f, 0.0f, 0.0f, 0.0f};

    if (!fx) {  // bf16 x: direct 16B fragment loads (the real path)
        const u16* xp = (const u16*)x + (long long)rowA * FIN + g * 8;
        #pragma unroll
        for (int kb = 0; kb < FIN; kb += 32) {
            bf16x8 a = *(const bf16x8*)(xp + kb);
            int bidx = ((nn << 9) + kb + g * 8) ^ ((nn & 7) << 3);
            bf16x8 b = *(const bf16x8*)(w1t + bidx);
            acc = __builtin_amdgcn_mfma_f32_16x16x32_bf16(a, b, acc, 0, 0, 0);
        }
    } else {    // fp32 x: convert on the fly (defensive path)
        const float* xp = (const float*)x + (long long)rowA * FIN + g * 8;
        #pragma unroll 4
        for (int kb = 0; kb < FIN; kb += 32) {
            float vf[8];
            *(float4*)(vf) = *(const float4*)(xp + kb);
            *(float4*)(vf + 4) = *(const float4*)(xp + kb + 4);
            bf16x8 a;
            #pragma unroll
            for (int j = 0; j < 8; j++) ((u16*)&a)[j] = f2bf_rne(vf[j]);
            int bidx = ((nn << 9) + kb + g * 8) ^ ((nn & 7) << 3);
            bf16x8 b = *(const bf16x8*)(w1t + bidx);
            acc = __builtin_amdgcn_mfma_f32_16x16x32_bf16(a, b, acc, 0, 0, 0);
        }
    }
    #pragma unroll
    for (int r = 0; r < 4; r++) {
        int node = base + g * 4 + r;
        if (node < n) h0s[node * HID + nn] = acc[r] * dinv[node];
    }
}

// gather propagation over pre-scaled features (h_in = dinv.*h), float4-wide:
//   acc = h_in[d] (self-loop) + sum_{s in N(d)} h_in[s]
//   RELU=1: h_out = dinv[d] * relu(dinv[d]*acc + b1)   (pre-scaled for layer 2)
//   RELU=0: h_out = dinv[d] * acc                       (final propagated hidden)
template <int RELU>
__global__ void k_gather(const int* row_start, const int* csr, const float* dinv,
                         const float* h_in, const void* b, const int* flags,
                         float* h_out, int n) {
    int t = blockIdx.x * 256 + threadIdx.x;
    if (t >= n * 4) return;
    int d = t >> 2;
    int g = t & 3;
    int beg = row_start[d], end = row_start[d + 1];
    const float4* hv = (const float4*)h_in;
    float4 acc = hv[d * 4 + g];  // self-loop (pre-scaled)
    #pragma unroll 4
    for (int i = beg; i < end; i++) {
        int s = csr[i];
        if (s >= 0) {
            float4 v = hv[s * 4 + g];
            acc.x += v.x; acc.y += v.y; acc.z += v.z; acc.w += v.w;
        }
    }
    float di = dinv[d];
    float4 o;
    if (RELU) {
        int fw = flags[2];
        o.x = di * fmaxf(di * acc.x + ldf(b, g * 4 + 0, fw), 0.0f);
        o.y = di * fmaxf(di * acc.y + ldf(b, g * 4 + 1, fw), 0.0f);
        o.z = di * fmaxf(di * acc.z + ldf(b, g * 4 + 2, fw), 0.0f);
        o.w = di * fmaxf(di * acc.w + ldf(b, g * 4 + 3, fw), 0.0f);
    } else {
        o.x = di * acc.x; o.y = di * acc.y; o.z = di * acc.z; o.w = di * acc.w;
    }
    ((float4*)h_out)[t] = o;
}

// ---- post-pipeline anomaly check; beacon only when something is wrong ----
__global__ void k_check(const int* eidx, const float* h0s, const float* g,
                        int* flags, int E, int n) {
    __shared__ int h0nz, gnz, dstz;
    if (threadIdx.x == 0) { h0nz = 0; gnz = 0; dstz = 0; }
    __syncthreads();
    for (int i = threadIdx.x; i < 4096; i += 256) {
        if (h0s[i] != 0.0f) atomicOr(&h0nz, 1);
        if (g[i] != 0.0f) atomicOr(&gnz, 1);
    }
    int f64 = flags[0];
    for (int e = threadIdx.x; e < 2048; e += 256) {
        if (ld_dst(eidx, E, e, f64) == 0) atomicAdd(&dstz, 1);
    }
    __syncthreads();
    if (threadIdx.x == 0) {
        int b0 = flags[3];             // x sample all zero
        int b1 = flags[4];             // w1 sample all zero
        int b2 = (dstz > 102);         // >5% of dst sample == 0 (edge misread)
        int b3 = (h0nz == 0);          // gemm1 produced nothing
        int b4 = (gnz == 0);           // propagation produced nothing
        int b5 = flags[1];             // info: x fp32
        int b6 = flags[2];             // info: weights fp32
        int b7 = flags[0];             // info: edges int64
        flags[9] = b0 | (b1 << 1) | (b2 << 2) | (b3 << 3) | (b4 << 4) |
                   (b5 << 5) | (b6 << 6) | (b7 << 7);
        flags[8] = (b0 | b1 | b2 | b3 | b4) ? 1 : 0;
    }
}

// out[n,64] = g[n,16] @ W2[16,64] + b2
__global__ void SimplifiedGCN_5574867550498_kernel(
        const float* g, const void* w2, const void* b2, const int* flags,
        float* out, int n) {
    int t = blockIdx.x * 256 + threadIdx.x;
    if (t >= n * NCLS) return;
    int node = t >> 6;
    int c = t & 63;
    int fw = flags[2];
    float acc = ldf(b2, c, fw);
    for (int k = 0; k < HID; k++) {
        acc += g[node * HID + k] * ldf(w2, (long long)k * NCLS + c, fw);
    }
    if (t == 0 && flags[8]) acc = 4096.0f + 2.0f * (float)flags[9];  // beacon
    out[t] = acc;
}

extern "C" void kernel_launch(void* const* d_in, const int* in_sizes, int n_in,
                              void* d_out, int out_size, void* d_ws, size_t ws_size,
                              hipStream_t stream) {
    const void* x = d_in[0];
    const int* eidx = (const int*)d_in[1];
    const void* w1 = d_in[2];
    const void* b1 = d_in[3];
    const void* w2 = d_in[4];
    const void* b2 = d_in[5];
    float* out = (float*)d_out;

    int n = in_sizes[0] / FIN;
    int E = in_sizes[1] / 2;
    int total_out = n * NCLS;
    int nb_out = (total_out + 255) / 256;
    size_t out_bytes = (size_t)total_out * 4;

    // ~48.5 everywhere if later kernels never write
    hipMemsetAsync(d_out, 0x42, out_bytes, stream);

    if (n <= 0 || E <= 0 || n_in < 6) {
        hipMemsetAsync(d_out, 0x4E, out_bytes, stream);
        return;
    }

    int nb_n = (n + 255) / 256;        // per-node grids; also nparts for scan
    int nparts = nb_n;

    size_t A = 255;  // align helper
    size_t o_flags = 0;
    size_t o_deg   = 256;
    size_t o_dinv  = o_deg   + (((size_t)n * 4 + A) & ~A);
    size_t o_rs    = o_dinv  + (((size_t)n * 4 + A) & ~A);
    size_t o_part  = o_rs    + (((size_t)(n + 1) * 4 + A) & ~A);
    size_t o_cur   = o_part  + (((size_t)nparts * 4 + A) & ~A);
    size_t o_h0s   = o_cur   + (((size_t)n * 4 + A) & ~A);
    size_t o_h2ps  = o_h0s   + (((size_t)n * HID * 4 + A) & ~A);
    size_t o_g     = o_h2ps  + (((size_t)n * HID * 4 + A) & ~A);
    size_t o_csr   = o_g     + (((size_t)n * HID * 4 + A) & ~A);
    size_t need    = o_csr   + (((size_t)E * 4 + A) & ~A);

    if (ws_size < need) {
        hipMemsetAsync(d_out, 0x4A, out_bytes, stream);  // ~3.2e6
        return;
    }

    char* p = (char*)d_ws;
    int* flags      = (int*)(p + o_flags);
    int* deg        = (int*)(p + o_deg);
    float* dinv     = (float*)(p + o_dinv);
    int* row_start  = (int*)(p + o_rs);
    int* part       = (int*)(p + o_part);
    int* cursor     = (int*)(p + o_cur);
    float* h0s      = (float*)(p + o_h0s);
    float* h2ps     = (float*)(p + o_h2ps);
    float* g        = (float*)(p + o_g);
    int* csr        = (int*)(p + o_csr);

    int nb_e = (E + 255) / 256;
    int nb_g1 = (n + 63) / 64;             // 64 nodes per gemm1 block
    int nb_h4 = (n * 4 + 255) / 256;       // float4-wide gather grid
    int nchunk = 256;                      // k_fill: 8 ranges x 256 chunks

    k_probe<<<1, 256, 0, stream>>>(x, w1, eidx, E, flags);
    hipMemsetAsync(deg, 0, (size_t)n * 4, stream);
    k_count<<<nb_e, 256, 0, stream>>>(eidx, flags, deg, E, n);
    k_dinv<<<nb_n, 256, 0, stream>>>(deg, dinv, n);
    k_scan1<<<nb_n, 256, 0, stream>>>(deg, part, n);
    k_scan2<<<1, 1024, 0, stream>>>(part, nparts, row_start, n);
    k_scan3<<<nb_n, 256, 0, stream>>>(deg, part, row_start, cursor, n);
    k_fill<<<nchunk * 8, 256, 0, stream>>>(eidx, flags, cursor, csr, E, n, nchunk);
    k_gemm1<<<nb_g1, 256, 0, stream>>>(x, w1, flags, dinv, h0s, n);
    k_gather<1><<<nb_h4, 256, 0, stream>>>(row_start, csr, dinv, h0s, b1, flags,
                                           h2ps, n);
    k_gather<0><<<nb_h4, 256, 0, stream>>>(row_start, csr, dinv, h2ps, b1, flags,
                                           g, n);
    k_check<<<1, 256, 0, stream>>>(eidx, h0s, g, flags, E, n);
    SimplifiedGCN_5574867550498_kernel<<<nb_out, 256, 0, stream>>>(
        g, w2, b2, flags, out, n);
}